// Round 1
// baseline (4221.507 us; speedup 1.0000x reference)
//
#include <hip/hip_runtime.h>

using u16 = unsigned short;
using u32 = unsigned int;
using u64 = unsigned long long;

typedef short bf16x8 __attribute__((ext_vector_type(8)));
typedef float f32x4 __attribute__((ext_vector_type(4)));

#define TB 16
#define TT 256
#define TV 32000
#define TE 256
#define TH 512

__device__ __forceinline__ u16 f2bf(float f) {
    u32 u = __builtin_bit_cast(u32, f);
    u32 r = (u + 0x7FFFu + ((u >> 16) & 1u)) >> 16;
    return (u16)r;
}

__device__ __forceinline__ f32x4 mfma16(bf16x8 a, bf16x8 b, f32x4 c) {
    return __builtin_amdgcn_mfma_f32_16x16x32_bf16(a, b, c, 0, 0, 0);
}

// ---------------- kernel 1: embedding gather -> bf16 x[b][t][e] ----------------
__global__ void k_embed(const int* __restrict__ inp, const float* __restrict__ emb,
                        u16* __restrict__ xbf) {
    int row = blockIdx.x;            // b*T + t
    int tok = inp[row];
    int e = threadIdx.x;             // 256 threads = E
    xbf[(size_t)row * TE + e] = f2bf(emb[(size_t)tok * TE + e]);
}

// ---------------- kernel 2: fc_w (1024,32000) f32 -> fcwT (32000,1024) bf16 ----
__global__ void k_fcw_t(const float* __restrict__ w, u16* __restrict__ wt) {
    __shared__ float tile[32][33];
    int v0 = blockIdx.x * 32, k0 = blockIdx.y * 32;
    int tx = threadIdx.x, ty = threadIdx.y;   // (32,8)
#pragma unroll
    for (int i = 0; i < 4; ++i)
        tile[ty * 4 + i][tx] = w[(size_t)(k0 + ty * 4 + i) * TV + v0 + tx];
    __syncthreads();
#pragma unroll
    for (int i = 0; i < 4; ++i)
        wt[(size_t)(v0 + ty * 4 + i) * 1024 + k0 + tx] = f2bf(tile[tx][ty * 4 + i]);
}

// ---------------- kernel 3: persistent bidirectional LSTM recurrence ----------
// 32 blocks: blockIdx = dir*16 + slice. Each block: 4 waves, each wave owns 2
// col-tiles (16 cols each) of the 128 gate-columns (col = j*4 + g).
// Wh slice (512x128) + Wx slice (256x128) live in VGPRs as bf16 B-fragments.
// h exchange: htag[dir][slot][b][k] u32 = (tag << 16) | bf16(h), agent-scope
// relaxed atomics, tag for h produced at step t is t+1. Step t reads slot
// (t+1)&1 expecting tag t, writes slot t&1 with tag t+1. Double-buffer is
// race-free because a writer of h_{t+1} has consumed all of h_t, implying all
// h_{t-1} reads (same slot) completed.
__global__ __launch_bounds__(256, 1) void k_lstm(
    const u16* __restrict__ xbf,
    const float* __restrict__ WhF, const float* __restrict__ WxF, const float* __restrict__ bF,
    const float* __restrict__ WhB, const float* __restrict__ WxB, const float* __restrict__ bB,
    u32* __restrict__ htag, u16* __restrict__ hall) {
    const int tid = threadIdx.x;
    const int w = tid >> 6;
    const int l = tid & 63;
    const int dir = blockIdx.x >> 4;
    const int s = blockIdx.x & 15;
    const float* Wh = dir ? WhB : WhF;
    const float* Wx = dir ? WxB : WxF;
    const float* bb = dir ? bB : bF;

    const int g = l & 3;            // gate of this lane's output columns
    const int lz = l >> 4;          // k-group / row-group
    const int j0 = w * 8 + ((l & 15) >> 2);   // slice-local h dim, tile 0
    const int j1 = j0 + 4;                     // tile 1
    const int hout0 = s * 32 + j0;
    const int hout1 = s * 32 + j1;

    // ---- preload weight fragments (once) ----
    bf16x8 whf0[16], whf1[16];
#pragma unroll
    for (int kt = 0; kt < 16; ++kt) {
        int kb = kt * 32 + lz * 8;
#pragma unroll
        for (int i = 0; i < 8; ++i) {
            whf0[kt][i] = (short)f2bf(Wh[(size_t)g * TH * TH + (size_t)(kb + i) * TH + hout0]);
            whf1[kt][i] = (short)f2bf(Wh[(size_t)g * TH * TH + (size_t)(kb + i) * TH + hout1]);
        }
    }
    bf16x8 wxf0[8], wxf1[8];
#pragma unroll
    for (int kt = 0; kt < 8; ++kt) {
        int kb = kt * 32 + lz * 8;
#pragma unroll
        for (int i = 0; i < 8; ++i) {
            wxf0[kt][i] = (short)f2bf(Wx[(size_t)g * TE * TH + (size_t)(kb + i) * TH + hout0]);
            wxf1[kt][i] = (short)f2bf(Wx[(size_t)g * TE * TH + (size_t)(kb + i) * TH + hout1]);
        }
    }
    const float bias0 = bb[g * TH + hout0];
    const float bias1 = bb[g * TH + hout1];

    float c0s[4] = {0.f, 0.f, 0.f, 0.f};
    float c1s[4] = {0.f, 0.f, 0.f, 0.f};
    const int bx = l & 15;                       // A-matrix row = batch
    u32* hdir = htag + dir * (2 * 16 * 512);
    const u16* xrow_base = xbf + (size_t)bx * TT * TE;
    const u64 TAGMASK = 0xFFFF0000FFFF0000ULL;

    for (int t = 0; t < TT; ++t) {
        const int t_eff = dir ? (TT - 1 - t) : t;
        f32x4 acc0 = {0.f, 0.f, 0.f, 0.f};
        f32x4 acc1 = {0.f, 0.f, 0.f, 0.f};

        u64* hb = (u64*)(hdir + ((t + 1) & 1) * (16 * 512) + bx * 512);
        const u64 expw = ((u64)(u32)t << 16) | ((u64)(u32)t << 48);

        // issue first h-group loads early so latency hides under x-part
        u64 gbuf[2][16];
#pragma unroll
        for (int q = 0; q < 16; ++q)
            gbuf[0][q] = __hip_atomic_load(hb + (q >> 2) * 16 + lz * 4 + (q & 3),
                                           __ATOMIC_RELAXED, __HIP_MEMORY_SCOPE_AGENT);

        // x-part: acc += x_t * Wx  (independent of h)
        const u16* xrow = xrow_base + (size_t)t_eff * TE;
#pragma unroll
        for (int kt = 0; kt < 8; ++kt) {
            bf16x8 ax = *(const bf16x8*)(xrow + kt * 32 + lz * 8);
            acc0 = mfma16(ax, wxf0[kt], acc0);
            acc1 = mfma16(ax, wxf1[kt], acc1);
        }

        // h-part: 4 groups of 4 k-tiles, double-buffered prefetch
#pragma unroll
        for (int gr = 0; gr < 4; ++gr) {
            const int cur = gr & 1, nxt = cur ^ 1;
            if (gr < 3) {
#pragma unroll
                for (int q = 0; q < 16; ++q)
                    gbuf[nxt][q] = __hip_atomic_load(
                        hb + ((gr + 1) * 4 + (q >> 2)) * 16 + lz * 4 + (q & 3),
                        __ATOMIC_RELAXED, __HIP_MEMORY_SCOPE_AGENT);
            }
            // spin until all 16 words of this group carry tag t
            while (true) {
                u64 x = 0;
#pragma unroll
                for (int q = 0; q < 16; ++q) x |= (gbuf[cur][q] ^ expw);
                if ((x & TAGMASK) == 0) break;
#pragma unroll
                for (int q = 0; q < 16; ++q)
                    gbuf[cur][q] = __hip_atomic_load(
                        hb + (gr * 4 + (q >> 2)) * 16 + lz * 4 + (q & 3),
                        __ATOMIC_RELAXED, __HIP_MEMORY_SCOPE_AGENT);
            }
#pragma unroll
            for (int k2 = 0; k2 < 4; ++k2) {
                const int kt = gr * 4 + k2;
                u64 w0 = gbuf[cur][k2 * 4 + 0];
                u64 w1 = gbuf[cur][k2 * 4 + 1];
                u64 w2 = gbuf[cur][k2 * 4 + 2];
                u64 w3 = gbuf[cur][k2 * 4 + 3];
                bf16x8 ah;
                ah[0] = (short)(u16)w0; ah[1] = (short)(u16)(w0 >> 32);
                ah[2] = (short)(u16)w1; ah[3] = (short)(u16)(w1 >> 32);
                ah[4] = (short)(u16)w2; ah[5] = (short)(u16)(w2 >> 32);
                ah[6] = (short)(u16)w3; ah[7] = (short)(u16)(w3 >> 32);
                acc0 = mfma16(ah, whf0[kt], acc0);
                acc1 = mfma16(ah, whf1[kt], acc1);
            }
        }

        // elementwise LSTM cell (gates live in quads: lane g = l&3)
        u32* hwr = hdir + (t & 1) * (16 * 512);
#pragma unroll
        for (int tau = 0; tau < 2; ++tau) {
            f32x4 acc = tau ? acc1 : acc0;
            const float bias = tau ? bias1 : bias0;
            const int hd = tau ? hout1 : hout0;
            float* cs = tau ? c1s : c0s;
#pragma unroll
            for (int r = 0; r < 4; ++r) {
                float pre = acc[r] + bias;
                int qb = l & ~3;
                float vi = __shfl(pre, qb + 0, 64);
                float vf = __shfl(pre, qb + 1, 64);
                float vo = __shfl(pre, qb + 2, 64);
                float vc = __shfl(pre, qb + 3, 64);
                float gi = 1.0f / (1.0f + __expf(-vi));
                float gf = 1.0f / (1.0f + __expf(-vf));
                float go = 1.0f / (1.0f + __expf(-vo));
                float gc = tanhf(vc);
                float c = gf * cs[r] + gi * gc;
                cs[r] = c;
                float h = go * tanhf(c);
                if (g == 0) {
                    int b = lz * 4 + r;
                    u32 val = (((u32)(t + 1)) << 16) | (u32)f2bf(h);
                    __hip_atomic_store(hwr + b * 512 + hd, val,
                                       __ATOMIC_RELAXED, __HIP_MEMORY_SCOPE_AGENT);
                    hall[((size_t)b * TT + t_eff) * 1024 + dir * 512 + hd] = f2bf(h);
                }
            }
        }
    }
}

// ---------------- kernel 4: FC GEMM  out = hall(4096x1024) @ fcwT^T + fc_b ----
// 128x128 tile, BK=32, 256 threads (4 waves, each 64x64), bf16 MFMA.
__global__ __launch_bounds__(256) void k_fc(const u16* __restrict__ A, const u16* __restrict__ Bt,
                                            const float* __restrict__ bias, float* __restrict__ out) {
    __shared__ __align__(16) u16 Ash[128 * 32];
    __shared__ __align__(16) u16 Bsh[128 * 32];
    const int tid = threadIdx.x;
    const int l = tid & 63, wv = tid >> 6;
    const int bid = blockIdx.x;
    const int o = (bid & 7) * 1000 + (bid >> 3);   // XCD-contiguous traversal
    const int mb = o & 31, nb = o >> 5;            // mb: 0..31, nb: 0..249
    const int r_st = tid >> 2;
    const int k_st = (tid & 3) * 8;
    const u16* Abase = A + (size_t)(mb * 128) * 1024;
    const u16* Bbase = Bt + (size_t)(nb * 128) * 1024;
    const int wr = wv >> 1, wc = wv & 1;
    const int lr = l & 15, lk = (l >> 4) * 8;
    f32x4 acc[4][4] = {};

    for (int kk = 0; kk < 32; ++kk) {
        uint4 a0 = *(const uint4*)(Abase + (size_t)r_st * 1024 + kk * 32 + k_st);
        uint4 a1 = *(const uint4*)(Abase + (size_t)(64 + r_st) * 1024 + kk * 32 + k_st);
        uint4 b0 = *(const uint4*)(Bbase + (size_t)r_st * 1024 + kk * 32 + k_st);
        uint4 b1 = *(const uint4*)(Bbase + (size_t)(64 + r_st) * 1024 + kk * 32 + k_st);
        __syncthreads();
        *(uint4*)&Ash[r_st * 32 + k_st] = a0;
        *(uint4*)&Ash[(64 + r_st) * 32 + k_st] = a1;
        *(uint4*)&Bsh[r_st * 32 + k_st] = b0;
        *(uint4*)&Bsh[(64 + r_st) * 32 + k_st] = b1;
        __syncthreads();
        bf16x8 af[4], bfr[4];
#pragma unroll
        for (int i = 0; i < 4; ++i)
            af[i] = *(const bf16x8*)&Ash[(wr * 64 + i * 16 + lr) * 32 + lk];
#pragma unroll
        for (int j = 0; j < 4; ++j)
            bfr[j] = *(const bf16x8*)&Bsh[(wc * 64 + j * 16 + lr) * 32 + lk];
#pragma unroll
        for (int i = 0; i < 4; ++i)
#pragma unroll
            for (int j = 0; j < 4; ++j)
                acc[i][j] = mfma16(af[i], bfr[j], acc[i][j]);
    }

    const int row0 = mb * 128 + wr * 64;
    const int col0 = nb * 128 + wc * 64 + lr;
#pragma unroll
    for (int j = 0; j < 4; ++j) {
        float bj = bias[col0 + j * 16];
#pragma unroll
        for (int i = 0; i < 4; ++i) {
#pragma unroll
            for (int r = 0; r < 4; ++r) {
                int row = row0 + i * 16 + (l >> 4) * 4 + r;
                out[(size_t)row * TV + col0 + j * 16] = acc[i][j][r] + bj;
            }
        }
    }
}

// ---------------- launcher ----------------
extern "C" void kernel_launch(void* const* d_in, const int* in_sizes, int n_in,
                              void* d_out, int out_size, void* d_ws, size_t ws_size,
                              hipStream_t stream) {
    const int*   inputs = (const int*)  d_in[0];
    const float* emb    = (const float*)d_in[1];
    const float* Wh_f   = (const float*)d_in[2];
    const float* Wx_f   = (const float*)d_in[3];
    const float* b_f    = (const float*)d_in[4];
    const float* Wh_b   = (const float*)d_in[5];
    const float* Wx_b   = (const float*)d_in[6];
    const float* b_b    = (const float*)d_in[7];
    const float* fc_w   = (const float*)d_in[8];
    const float* fc_b   = (const float*)d_in[9];
    float* out = (float*)d_out;

    char* ws = (char*)d_ws;
    u16* xbf  = (u16*)(ws);                          // 4096*256*2      = 2,097,152
    u32* htag = (u32*)(ws + 2097152);                // 2*2*16*512*4    =   131,072
    u16* hall = (u16*)(ws + 2097152 + 131072);       // 4096*1024*2     = 8,388,608
    u16* fcwT = (u16*)(ws + 2097152 + 131072 + 8388608); // 32000*1024*2 = 65,536,000

    hipMemsetAsync(htag, 0, 131072, stream);
    k_embed<<<dim3(4096), dim3(256), 0, stream>>>(inputs, emb, xbf);
    k_fcw_t<<<dim3(TV / 32, 1024 / 32), dim3(32, 8), 0, stream>>>(fc_w, fcwT);
    k_lstm<<<dim3(32), dim3(256), 0, stream>>>(xbf, Wh_f, Wx_f, b_f,
                                               Wh_b, Wx_b, b_b, htag, hall);
    k_fc<<<dim3(8000), dim3(256), 0, stream>>>(hall, fcwT, fc_b, out);
}